// Round 3
// baseline (304.356 us; speedup 1.0000x reference)
//
#include <hip/hip_runtime.h>

// Problem constants (match reference)
#define C 80
#define P 30000
#define G 800
#define BS 256
#define NB 16         // 64-px cells over [0,1024); boxes binned by CENTER
#define NC (NB * NB)  // 256 cells per class
#define PPT 2         // sorted slots per thread in match
#define CH 20         // classes per scatter/match chunk (workspace cap)
#define NCHK (C / CH) // 4 chunks
#define HCH 8         // hist chunks per class
#define CHSZ ((P + HCH - 1) / HCH)   // 3750

// Center-binning prune (validated absmax 0.0 in rounds 1-2): IoU > 0.5 forces
// each box to contain the other's center in both dims -> |dc| < 64 px/dim ->
// all viable pairs lie in the 3x3 neighborhood of the pred's 64-px center
// cell. Pruned pairs provably have IoU <= 0.5; validity re-verified with the
// bit-exact reference division in the epilogue.
//
// Round-3 structure: counting-sort preds into cell order ONCE (materialize
// float4 box + ushort orig-index), then match reads slots coalesced. Lanes in
// a wave share a cell (~117 preds/cell) -> broadcast LDS reads (round-2's
// 30M bank-conflict cycles -> ~0), max-trip == mean-trip, full lane activity.
// GT-side LDS order and all pair arithmetic are bit-identical to round 2.

// rank order = score desc, then pred-index asc. Packed key is monotone in that
// order (scores >= 0 so float bits are order-preserving). key==0 means "no
// match" (needs score==0.0f AND p==P-1 — probability ~0).
__device__ __forceinline__ unsigned long long pack_key(float s, int p) {
    return ((unsigned long long)__float_as_uint(s) << 32) | (unsigned)(P - 1 - p);
}

__device__ __forceinline__ int cell_of_center(float cxf, float cyf) {
    int bx = min(max((int)(cxf * (1.0f / 64.0f)), 0), NB - 1);
    int by = min(max((int)(cyf * (1.0f / 64.0f)), 0), NB - 1);
    return by * NB + bx;
}

// ---------------- gt binning: one block per class (count+scan+scatter) ------
// BS == NC == 256: thread t owns cell t. Also zeroes this class's gtKey,
// gHist, predCnt (init kernel folded in).
__global__ __launch_bounds__(BS) void gt_bin_kernel(
        const float* __restrict__ gt,
        unsigned short* __restrict__ gtCnt, unsigned short* __restrict__ gtOff,
        float4* __restrict__ gtBox, float* __restrict__ gtAbe,
        unsigned short* __restrict__ gtIdx,
        unsigned long long* __restrict__ gtKey, int* __restrict__ gHist,
        int* __restrict__ predCnt) {
    __shared__ int h[NC], cur[NC];
    __shared__ int gcell[G];
    const int c = blockIdx.x, tid = threadIdx.x;
    h[tid] = 0;
    predCnt[c * NC + tid] = 0;                                       // folded init
    for (int i = tid; i < G; i += BS) gtKey[c * G + i] = 0ull;       // folded init
    for (int j = tid; j < 1024; j += BS) gHist[c * 1024 + j] = 0;    // folded init
    __syncthreads();
    for (int i = tid; i < G; i += BS) {
        const float* r = gt + ((size_t)c * G + i) * 7;
        int cl = cell_of_center(0.5f * (r[3] + r[5]), 0.5f * (r[4] + r[6]));
        gcell[i] = cl;
        atomicAdd(&h[cl], 1);
    }
    __syncthreads();
    const int v = h[tid];
    cur[tid] = v;
    __syncthreads();
    for (int o = 1; o < NC; o <<= 1) {   // inclusive scan, 8 steps
        int t = (tid >= o) ? cur[tid - o] : 0;
        __syncthreads();
        cur[tid] += t;
        __syncthreads();
    }
    const int excl = cur[tid] - v;
    gtOff[c * NC + tid] = (unsigned short)excl;
    gtCnt[c * NC + tid] = (unsigned short)v;
    __syncthreads();
    cur[tid] = excl;
    __syncthreads();
    for (int i = tid; i < G; i += BS) {
        const float* r = gt + ((size_t)c * G + i) * 7;   // L1-hot (2nd pass)
        float x1 = r[3], y1 = r[4], x2 = r[5], y2 = r[6];
        int slot = atomicAdd(&cur[gcell[i]], 1);
        gtBox[c * G + slot] = make_float4(x1, y1, x2, y2);
        // area + eps pre-folded: cross-compare uses sb = A + (area_g + eps);
        // the -inter terms of the two denominators cancel algebraically.
        gtAbe[c * G + slot] = __fadd_rn(__fmul_rn(__fsub_rn(x2, x1), __fsub_rn(y2, y1)), 1e-9f);
        gtIdx[c * G + slot] = (unsigned short)i;
    }
}

// ---------------- pred prep: per-(class,cell) counts + score extraction -----
__global__ __launch_bounds__(BS) void pred_prep_kernel(
        const float* __restrict__ pred, int* __restrict__ predCnt,
        float* __restrict__ scoreC) {
    __shared__ int h[NC];
    const int c = blockIdx.y, tid = threadIdx.x;
    h[tid] = 0;
    __syncthreads();
    int p = blockIdx.x * BS + tid;
    if (p < P) {
        const float* r = pred + ((size_t)c * P + p) * 7;
        scoreC[(size_t)c * P + p] = r[2];
        int cl = cell_of_center(0.5f * (r[3] + r[5]), 0.5f * (r[4] + r[6]));
        atomicAdd(&h[cl], 1);
    }
    __syncthreads();
    if (h[tid]) atomicAdd(&predCnt[c * NC + tid], h[tid]);   // no-return
}

// ---------------- pred scan: one 256-thread block per class ----------------
__global__ __launch_bounds__(NC) void pred_scan_kernel(
        const int* __restrict__ predCnt,
        unsigned short* __restrict__ predOff, int* __restrict__ predCur) {
    __shared__ int sc[NC];
    const int c = blockIdx.x, tid = threadIdx.x;
    const int v = predCnt[c * NC + tid];
    sc[tid] = v;
    __syncthreads();
    for (int o = 1; o < NC; o <<= 1) {
        int t = (tid >= o) ? sc[tid - o] : 0;
        __syncthreads();
        sc[tid] += t;
        __syncthreads();
    }
    const int excl = sc[tid] - v;
    predOff[c * NC + tid] = (unsigned short)excl;   // offsets < P < 65536
    predCur[c * NC + tid] = excl;
}

// ---------------- pred scatter: materialize cell-sorted box records --------
// Per chunk of CH classes. LDS-aggregated slot reservation (one global atomic
// per nonempty cell per block). Order within a cell is arbitrary — match
// treats same-cell preds symmetrically (argmax keyed by GT index j; pred
// identity carried by pIdxS).
__global__ __launch_bounds__(BS) void pred_scatter_kernel(
        const float* __restrict__ pred, int* __restrict__ predCur,
        float4* __restrict__ predSorted, unsigned short* __restrict__ pIdxS,
        int c0) {
    __shared__ int h[NC], base[NC];
    const int cl_loc = blockIdx.y, c = c0 + cl_loc, tid = threadIdx.x;
    h[tid] = 0;
    __syncthreads();
    int p = blockIdx.x * BS + tid;
    int cellv = 0, lr = 0;
    float4 box = make_float4(0.f, 0.f, 0.f, 0.f);
    if (p < P) {
        const float* r = pred + ((size_t)c * P + p) * 7;
        box = make_float4(r[3], r[4], r[5], r[6]);
        cellv = cell_of_center(0.5f * (box.x + box.z), 0.5f * (box.y + box.w));
        lr = atomicAdd(&h[cellv], 1);   // LDS, local rank
    }
    __syncthreads();
    if (h[tid]) base[tid] = atomicAdd(&predCur[c * NC + tid], h[tid]);
    __syncthreads();
    if (p < P) {
        int slot = base[cellv] + lr;
        predSorted[(size_t)cl_loc * P + slot] = box;
        pIdxS[(size_t)cl_loc * P + slot] = (unsigned short)p;
    }
}

// ---------------- match: coalesced sorted slots, whole-class GT in LDS ------
// Block covers PPT*BS consecutive SORTED slots of one class: lanes in a wave
// share a cell (~117 preds/cell) -> per-lane (jb,je) nearly wave-uniform ->
// LDS reads broadcast (no bank conflicts), loop trip == mean trip, all lanes
// active, predSorted reads fully coalesced (float4). Pair arithmetic and GT
// ordering bit-identical to round 2 (absmax 0.0). Score fetched only in the
// rare iou>0.5 epilogue.
__global__ __launch_bounds__(BS) void match5_kernel(
        const float4* __restrict__ predSorted, const unsigned short* __restrict__ pIdxS,
        const unsigned short* __restrict__ gtOff, const unsigned short* __restrict__ gtCnt,
        const float4* __restrict__ gtBox, const float* __restrict__ gtAbe,
        const unsigned short* __restrict__ gtIdx,
        const float* __restrict__ scoreC,
        unsigned long long* __restrict__ gtKey, int c0) {
    __shared__ float sX1[G], sY1[G], sX2[G], sY2[G], sE[G];
    __shared__ unsigned short sG[G];
    __shared__ unsigned short sOff[NC], sCnt[NC];
    const int cl_loc = blockIdx.y, c = c0 + cl_loc, tid = threadIdx.x;

    for (int i = tid; i < G; i += BS) {
        float4 b = gtBox[c * G + i];
        sX1[i] = b.x; sY1[i] = b.y; sX2[i] = b.z; sY2[i] = b.w;
        sE[i] = gtAbe[c * G + i];
        sG[i] = gtIdx[c * G + i];
    }
    sOff[tid] = gtOff[c * NC + tid];   // BS == NC
    sCnt[tid] = gtCnt[c * NC + tid];
    __syncthreads();

    const size_t cpl = (size_t)cl_loc * P;
    #pragma unroll
    for (int rep = 0; rep < PPT; ++rep) {
        const int s = (blockIdx.x * PPT + rep) * BS + tid;
        if (s < P) {
            float4 b4 = predSorted[cpl + s];
            float ax1 = b4.x, ay1 = b4.y, ax2 = b4.z, ay2 = b4.w;
            float A = __fmul_rn(__fsub_rn(ax2, ax1), __fsub_rn(ay2, ay1));
            int cell = cell_of_center(0.5f * (ax1 + ax2), 0.5f * (ay1 + ay2));
            int cx = cell & (NB - 1), cy = cell >> 4;
            int x0 = max(cx - 1, 0), x1 = min(cx + 1, NB - 1);
            int y0 = max(cy - 1, 0), y1 = min(cy + 1, NB - 1);
            float IN = 0.0f, SB = 1.0f;
            int mj = -1;
            for (int yy = y0; yy <= y1; ++yy) {
                const int rowb = yy * NB;
                const int jb = sOff[rowb + x0];
                const int je = sOff[rowb + x1] + sCnt[rowb + x1];
                for (int j = jb; j < je; ++j) {
                    float bx1 = sX1[j], by1 = sY1[j];
                    float bx2 = sX2[j], by2 = sY2[j];
                    float lx = fmaxf(ax1, bx1), ly = fmaxf(ay1, by1);
                    float rx = fminf(ax2, bx2), ry = fminf(ay2, by2);
                    float wx = fmaxf(__fsub_rn(rx, lx), 0.0f);
                    float wy = fmaxf(__fsub_rn(ry, ly), 0.0f);
                    float in = __fmul_rn(wx, wy);
                    float sb = __fadd_rn(A, sE[j]);
                    bool  up = __fmul_rn(in, SB) > __fmul_rn(IN, sb);
                    IN = up ? in : IN; SB = up ? sb : SB; mj = up ? j : mj;
                }
            }
            if (IN > 0.0f) {   // zero-inter preds can never be valid
                float bx1 = sX1[mj], by1 = sY1[mj], bx2 = sX2[mj], by2 = sY2[mj];
                float area = __fmul_rn(__fsub_rn(bx2, bx1), __fsub_rn(by2, by1));
                float dn = __fadd_rn(__fsub_rn(__fadd_rn(A, area), IN), 1e-9f);
                float iou = __fdiv_rn(IN, dn);   // exact reference value
                if (iou > 0.5f) {
                    int p = pIdxS[cpl + s];                  // rare path
                    float sscore = scoreC[(size_t)c * P + p];
                    atomicMax(&gtKey[c * G + sG[mj]], pack_key(sscore, p));
                }
            }
        }
    }
}

// ---------------- sortc: compact gtKey + position-sort, one block/class -----
__global__ __launch_bounds__(BS) void sortc_kernel(
        const unsigned long long* __restrict__ gtKey,
        unsigned long long* __restrict__ sortedKeys, int* __restrict__ sortT) {
    __shared__ unsigned long long k[G];
    __shared__ unsigned long long sk[1024];
    __shared__ int cnt;
    const int c = blockIdx.x, tid = threadIdx.x;
    if (tid == 0) cnt = 0;
    for (int j = tid; j < 1024; j += BS) sk[j] = 0ull;
    __syncthreads();
    for (int i = tid; i < G; i += BS) {
        unsigned long long key = gtKey[c * G + i];
        if (key != 0ull) k[atomicAdd(&cnt, 1)] = key;
    }
    __syncthreads();
    const int T = cnt;
    if (tid == 0) sortT[c] = T;
    for (int t = tid; t < T; t += BS) {
        unsigned long long key = k[t];
        int pos = 0;
        for (int u = 0; u < T; ++u) pos += (k[u] > key) ? 1 : 0;   // keys unique
        sk[pos] = key;
    }
    __syncthreads();
    for (int j = tid; j < 1024; j += BS) sortedKeys[c * 1024 + j] = sk[j];
}

// ---------------- hist: pos(q) for every pred via binary search ----------
__global__ __launch_bounds__(BS) void hist_kernel(
        const float* __restrict__ scoreC,
        const unsigned long long* __restrict__ sortedKeys,
        int* __restrict__ gHist) {
    __shared__ unsigned long long sK[1024];
    __shared__ int h[1024];
    const int c = blockIdx.y, tid = threadIdx.x;
    for (int j = tid; j < 1024; j += BS) { sK[j] = sortedKeys[c * 1024 + j]; h[j] = 0; }
    __syncthreads();
    const int start = blockIdx.x * CHSZ;
    const int end   = min(start + CHSZ, P);
    const float* sc = scoreC + (size_t)c * P;
    for (int i = start + tid; i < end; i += BS) {
        unsigned long long kq =
            ((unsigned long long)__float_as_uint(sc[i]) << 32) | (unsigned)(P - 1 - i);
        int lo = 0;   // count of sorted-desc keys > kq (pads are 0, never > kq)
        #pragma unroll
        for (int step = 512; step > 0; step >>= 1)
            if (sK[lo + step - 1] > kq) lo += step;
        atomicAdd(&h[lo], 1);
    }
    __syncthreads();
    for (int j = tid; j < 1024; j += BS)
        if (h[j]) atomicAdd(&gHist[c * 1024 + j], h[j]);   // no-return
}

// ---------------- ap: prefix over hist + closed-form terms ----------------
__global__ __launch_bounds__(BS) void ap2_kernel(
        const int* __restrict__ sortT, const int* __restrict__ gHist,
        float* __restrict__ ap) {
    __shared__ int ha[1024];
    __shared__ int hb[1024];
    __shared__ float red[BS];
    const int c = blockIdx.x, tid = threadIdx.x;
    const int T = sortT[c];
    for (int j = tid; j < 1024; j += BS) ha[j] = gHist[c * 1024 + j];
    __syncthreads();
    int* src = ha; int* dst = hb;
    for (int o = 1; o < 1024; o <<= 1) {
        for (int j = tid; j < 1024; j += BS)
            dst[j] = src[j] + ((j >= o) ? src[j - o] : 0);
        __syncthreads();
        int* tmp = src; src = dst; dst = tmp;
    }
    float sum = 0.0f;
    for (int s = tid; s < T; s += BS) {
        int r = src[s] - 1;          // inclusive prefix minus self
        if (r >= 1) {
            float kf  = (float)(s + 1);
            float km  = (float)s;
            float ri  = __fdiv_rn(kf, 800.0f);
            float rim = __fdiv_rn(km, 800.0f);
            float pi  = __fdiv_rn(kf, (float)(r + 1));
            float pim = __fdiv_rn(km, (float)r);
            sum = __fadd_rn(sum,
                  __fmul_rn(__fmul_rn(__fsub_rn(ri, rim), __fadd_rn(pi, pim)), 0.5f));
        }
    }
    red[tid] = sum;
    __syncthreads();
    for (int s2 = BS / 2; s2 > 0; s2 >>= 1) {
        if (tid < s2) red[tid] = __fadd_rn(red[tid], red[tid + s2]);
        __syncthreads();
    }
    if (tid == 0) ap[c] = red[0];
}

// ---------------- mean over classes ----------------
__global__ void mean_kernel(const float* __restrict__ ap, float* __restrict__ out) {
    if (threadIdx.x == 0) {
        float s = 0.0f;
        for (int c = 0; c < C; ++c) s = __fadd_rn(s, ap[c]);
        out[0] = __fdiv_rn(s, 80.0f);
    }
}

extern "C" void kernel_launch(void* const* d_in, const int* in_sizes, int n_in,
                              void* d_out, int out_size, void* d_ws, size_t ws_size,
                              hipStream_t stream) {
    const float* pred = (const float*)d_in[0];   // [C, P, 7] f32
    const float* gt   = (const float*)d_in[1];   // [C, G, 7] f32
    float* out = (float*)d_out;

    // Workspace layout — 23,508,864 B (under proven 24,734,464 B).
    // predSorted/pIdxS hold ONE chunk of CH=20 classes; the scatter->match
    // pair runs 4x sequentially reusing them. predCur aliases sortedKeys
    // (predCur dies after the last scatter; sortc later rewrites every
    // element of sortedKeys before hist/ap read it). Re-poisoned 0xAA each
    // call — gt_bin (incl. folded inits) / pred_scan / scatter / sortc
    // rewrite everything read-before-write.
    char* ws = (char*)d_ws;
    int*                sortT      = (int*)               (ws + 0);         //     320 B
    float*              ap         = (float*)             (ws + 512);       //     320 B
    int*                predCnt    = (int*)               (ws + 1024);      //  81920 B
    unsigned short*     predOff    = (unsigned short*)    (ws + 82944);     //  40960 B
    unsigned short*     gtCnt      = (unsigned short*)    (ws + 123904);    //  40960 B
    unsigned short*     gtOff      = (unsigned short*)    (ws + 164864);    //  40960 B
    unsigned short*     gtIdx      = (unsigned short*)    (ws + 205824);    // 128000 B
    unsigned short*     pIdxS      = (unsigned short*)    (ws + 333824);    // 1.2 MB (chunk)
    float*              gtAbe      = (float*)             (ws + 1533824);   // 256000 B
    float4*             gtBox      = (float4*)            (ws + 1789824);   // 1.024 MB (16-aligned)
    unsigned long long* gtKey      = (unsigned long long*)(ws + 2813824);   // 512000 B
    unsigned long long* sortedKeys = (unsigned long long*)(ws + 3325824);   // 655360 B
    int*                predCur    = (int*)               (ws + 3325824);   // ALIAS over sortedKeys
    int*                gHist      = (int*)               (ws + 3981184);   // 327680 B
    float*              scoreC     = (float*)             (ws + 4308864);   // 9.6 MB
    float4*             predSorted = (float4*)            (ws + 13908864);  // 9.6 MB (chunk, 16-aligned)
    // end: 23508864 B

    const int P_BLK = (P + BS - 1) / BS;                 // 118
    const int M_BLK = (P + BS * PPT - 1) / (BS * PPT);   // 59

    gt_bin_kernel<<<C, BS, 0, stream>>>(gt, gtCnt, gtOff, gtBox, gtAbe, gtIdx,
                                        gtKey, gHist, predCnt);
    pred_prep_kernel<<<dim3(P_BLK, C), BS, 0, stream>>>(pred, predCnt, scoreC);
    pred_scan_kernel<<<C, NC, 0, stream>>>(predCnt, predOff, predCur);
    for (int k = 0; k < NCHK; ++k) {
        const int c0 = k * CH;
        pred_scatter_kernel<<<dim3(P_BLK, CH), BS, 0, stream>>>(pred, predCur,
                                                                predSorted, pIdxS, c0);
        match5_kernel<<<dim3(M_BLK, CH), BS, 0, stream>>>(predSorted, pIdxS,
                                                          gtOff, gtCnt, gtBox, gtAbe, gtIdx,
                                                          scoreC, gtKey, c0);
    }
    sortc_kernel<<<C, BS, 0, stream>>>(gtKey, sortedKeys, sortT);
    hist_kernel<<<dim3(HCH, C), BS, 0, stream>>>(scoreC, sortedKeys, gHist);
    ap2_kernel<<<C, BS, 0, stream>>>(sortT, gHist, ap);
    mean_kernel<<<1, 64, 0, stream>>>(ap, out);
}

// Round 4
// 230.536 us; speedup vs baseline: 1.3202x; 1.3202x over previous
//
#include <hip/hip_runtime.h>

// Problem constants (match reference)
#define C 80
#define P 30000
#define G 800
#define BS 256
#define NB 16          // 64-px cells over [0,1024); boxes binned by CENTER
#define NC (NB * NB)   // 256 cells per class
#define PPT 8          // preds per thread in match
#define TPB (BS * PPT) // 2048 preds per match block (block-local sort granule)
#define HCH 8          // hist chunks per class
#define CHSZ ((P + HCH - 1) / HCH)   // 3750

// Center-binning prune (validated absmax 0.0 across rounds 1-3): IoU > 0.5
// forces each box to contain the other's center in both dims -> |dc| < 64
// px/dim -> all viable pairs lie in the 3x3 neighborhood of the pred's 64-px
// center cell. Pruned pairs provably have IoU <= 0.5; validity re-verified
// with the bit-exact reference division in the epilogue.
//
// Round-4 structure: round-2's 1-pass streaming match (fewest launches — the
// round-3 global sort showed per-launch gaps ~7-9us dominate) + BLOCK-LOCAL
// counting sort: 2048 preds/block sorted by cell in LDS, so a wave covers ~8
// distinct cells (8-way broadcast LDS reads, trip max ~= mean) instead of 64
// random ones (round-2's 30M bank-conflict cycles). Pred box re-gather in
// phase B is L2/L3-hot (pred is L3-resident; round-2 FETCH was 39MB < 67MB).

// rank order = score desc, then pred-index asc. Packed key is monotone in
// that order (scores >= 0 so float bits are order-preserving). key==0 means
// "no match" (needs score==0.0f AND p==P-1 — probability ~0).
__device__ __forceinline__ unsigned long long pack_key(float s, int p) {
    return ((unsigned long long)__float_as_uint(s) << 32) | (unsigned)(P - 1 - p);
}

__device__ __forceinline__ int cell_of_center(float cxf, float cyf) {
    int bx = min(max((int)(cxf * (1.0f / 64.0f)), 0), NB - 1);
    int by = min(max((int)(cyf * (1.0f / 64.0f)), 0), NB - 1);
    return by * NB + bx;
}

// ---------------- gt binning: one block per class (count+scan+scatter) ------
// BS == NC == 256: thread t owns cell t. Also zeroes this class's gtKey and
// gHist, and the ap2 ticket counter (init kernel folded in).
__global__ __launch_bounds__(BS) void gt_bin_kernel(
        const float* __restrict__ gt,
        unsigned short* __restrict__ gtCnt, unsigned short* __restrict__ gtOff,
        float4* __restrict__ gtBox, float* __restrict__ gtAbe,
        unsigned short* __restrict__ gtIdx,
        unsigned long long* __restrict__ gtKey, int* __restrict__ gHist,
        unsigned int* __restrict__ doneCnt) {
    __shared__ int h[NC], cur[NC];
    __shared__ int gcell[G];
    const int c = blockIdx.x, tid = threadIdx.x;
    h[tid] = 0;
    if (c == 0 && tid == 0) *doneCnt = 0u;                           // folded init
    for (int i = tid; i < G; i += BS) gtKey[c * G + i] = 0ull;       // folded init
    for (int j = tid; j < 1024; j += BS) gHist[c * 1024 + j] = 0;    // folded init
    __syncthreads();
    for (int i = tid; i < G; i += BS) {
        const float* r = gt + ((size_t)c * G + i) * 7;
        int cl = cell_of_center(0.5f * (r[3] + r[5]), 0.5f * (r[4] + r[6]));
        gcell[i] = cl;
        atomicAdd(&h[cl], 1);
    }
    __syncthreads();
    const int v = h[tid];
    cur[tid] = v;
    __syncthreads();
    for (int o = 1; o < NC; o <<= 1) {   // inclusive scan, 8 steps
        int t = (tid >= o) ? cur[tid - o] : 0;
        __syncthreads();
        cur[tid] += t;
        __syncthreads();
    }
    const int excl = cur[tid] - v;
    gtOff[c * NC + tid] = (unsigned short)excl;
    gtCnt[c * NC + tid] = (unsigned short)v;
    __syncthreads();
    cur[tid] = excl;
    __syncthreads();
    for (int i = tid; i < G; i += BS) {
        const float* r = gt + ((size_t)c * G + i) * 7;   // L1-hot (2nd pass)
        float x1 = r[3], y1 = r[4], x2 = r[5], y2 = r[6];
        int slot = atomicAdd(&cur[gcell[i]], 1);
        gtBox[c * G + slot] = make_float4(x1, y1, x2, y2);
        // area + eps pre-folded: cross-compare uses sb = A + (area_g + eps);
        // the -inter terms of the two denominators cancel algebraically.
        gtAbe[c * G + slot] = __fadd_rn(__fmul_rn(__fsub_rn(x2, x1), __fsub_rn(y2, y1)), 1e-9f);
        gtIdx[c * G + slot] = (unsigned short)i;
    }
}

// ---------------- match: streamed preds + block-local cell sort ----------
// Phase A: coalesced pass over the block's 2048 preds -> cell + LDS hist.
// Scan (proven 256-bin pattern) -> exclusive base. Scatter local indices into
// sorted order. Phase B: process preds in cell-sorted order — wave covers ~8
// cells -> LDS reads broadcast, trip max ~= mean; box re-gathered from global
// (L2/L3-hot). Pair arithmetic, GT order, and epilogue bit-identical to the
// proven rounds 2-3 kernels; processing order is irrelevant (atomicMax).
__global__ __launch_bounds__(BS) void match6_kernel(
        const float* __restrict__ pred,
        const unsigned short* __restrict__ gtOff, const unsigned short* __restrict__ gtCnt,
        const float4* __restrict__ gtBox, const float* __restrict__ gtAbe,
        const unsigned short* __restrict__ gtIdx,
        unsigned long long* __restrict__ gtKey) {
    __shared__ float sX1[G], sY1[G], sX2[G], sY2[G], sE[G];
    __shared__ unsigned short sG[G];
    __shared__ unsigned short sOff[NC], sCnt[NC];
    __shared__ unsigned char  sCell[TPB];
    __shared__ unsigned short sIdx[TPB];
    __shared__ int hcnt[NC], bb[NC];
    const int c = blockIdx.y, tid = threadIdx.x;
    const int p0 = blockIdx.x * TPB;
    const int cntP = min(TPB, P - p0);

    for (int i = tid; i < G; i += BS) {
        float4 b = gtBox[c * G + i];
        sX1[i] = b.x; sY1[i] = b.y; sX2[i] = b.z; sY2[i] = b.w;
        sE[i] = gtAbe[c * G + i];
        sG[i] = gtIdx[c * G + i];
    }
    sOff[tid] = gtOff[c * NC + tid];   // BS == NC
    sCnt[tid] = gtCnt[c * NC + tid];
    hcnt[tid] = 0;
    __syncthreads();

    const size_t cp = (size_t)c * P;

    // ---- phase A: coalesced cell computation + block histogram ----
    unsigned char  cellA[PPT];
    unsigned short lrA[PPT];
    #pragma unroll
    for (int rep = 0; rep < PPT; ++rep) {
        const int li = rep * BS + tid;
        const int p  = p0 + li;
        int cell = 0, lr = 0;
        if (p < P) {
            const float* r = pred + (cp + p) * 7;
            cell = cell_of_center(0.5f * (r[3] + r[5]), 0.5f * (r[4] + r[6]));
            lr = atomicAdd(&hcnt[cell], 1);
        }
        sCell[li] = (unsigned char)cell;
        cellA[rep] = (unsigned char)cell;
        lrA[rep] = (unsigned short)lr;
    }
    __syncthreads();

    // ---- scan 256 bins (proven pattern) -> exclusive base in bb ----
    const int v = hcnt[tid];
    __syncthreads();
    for (int o = 1; o < NC; o <<= 1) {
        int t = (tid >= o) ? hcnt[tid - o] : 0;
        __syncthreads();
        hcnt[tid] += t;
        __syncthreads();
    }
    bb[tid] = hcnt[tid] - v;
    __syncthreads();

    // ---- scatter local indices into cell-sorted order ----
    #pragma unroll
    for (int rep = 0; rep < PPT; ++rep) {
        const int li = rep * BS + tid;
        if (p0 + li < P) sIdx[bb[cellA[rep]] + lrA[rep]] = (unsigned short)li;
    }
    __syncthreads();

    // ---- phase B: pair loop in sorted order ----
    #pragma unroll 1
    for (int rep = 0; rep < PPT; ++rep) {
        const int si = rep * BS + tid;
        if (si < cntP) {
            const int li = sIdx[si];
            const int p  = p0 + li;
            const float* r = pred + (cp + p) * 7;     // L2/L3-hot re-gather
            float ax1 = r[3], ay1 = r[4], ax2 = r[5], ay2 = r[6];
            float A = __fmul_rn(__fsub_rn(ax2, ax1), __fsub_rn(ay2, ay1));
            const int cell = sCell[li];
            const int cx = cell & (NB - 1), cy = cell >> 4;
            const int x0 = max(cx - 1, 0), x1 = min(cx + 1, NB - 1);
            const int y0 = max(cy - 1, 0), y1 = min(cy + 1, NB - 1);
            float IN = 0.0f, SB = 1.0f;
            int mj = -1;
            for (int yy = y0; yy <= y1; ++yy) {
                const int rowb = yy * NB;
                const int jb = sOff[rowb + x0];
                const int je = sOff[rowb + x1] + sCnt[rowb + x1];
                for (int j = jb; j < je; ++j) {
                    float bx1 = sX1[j], by1 = sY1[j];
                    float bx2 = sX2[j], by2 = sY2[j];
                    float lx = fmaxf(ax1, bx1), ly = fmaxf(ay1, by1);
                    float rx = fminf(ax2, bx2), ry = fminf(ay2, by2);
                    float wx = fmaxf(__fsub_rn(rx, lx), 0.0f);
                    float wy = fmaxf(__fsub_rn(ry, ly), 0.0f);
                    float in = __fmul_rn(wx, wy);
                    float sb = __fadd_rn(A, sE[j]);
                    bool  up = __fmul_rn(in, SB) > __fmul_rn(IN, sb);
                    IN = up ? in : IN; SB = up ? sb : SB; mj = up ? j : mj;
                }
            }
            if (IN > 0.0f) {   // zero-inter preds can never be valid
                float bx1 = sX1[mj], by1 = sY1[mj], bx2 = sX2[mj], by2 = sY2[mj];
                float area = __fmul_rn(__fsub_rn(bx2, bx1), __fsub_rn(by2, by1));
                float dn = __fadd_rn(__fsub_rn(__fadd_rn(A, area), IN), 1e-9f);
                float iou = __fdiv_rn(IN, dn);   // exact reference value
                if (iou > 0.5f) {
                    float sscore = r[2];         // rare path
                    atomicMax(&gtKey[c * G + sG[mj]], pack_key(sscore, p));
                }
            }
        }
    }
}

// ---------------- sortc: compact gtKey + position-sort, one block/class -----
__global__ __launch_bounds__(BS) void sortc_kernel(
        const unsigned long long* __restrict__ gtKey,
        unsigned long long* __restrict__ sortedKeys, int* __restrict__ sortT) {
    __shared__ unsigned long long k[G];
    __shared__ unsigned long long sk[1024];
    __shared__ int cnt;
    const int c = blockIdx.x, tid = threadIdx.x;
    if (tid == 0) cnt = 0;
    for (int j = tid; j < 1024; j += BS) sk[j] = 0ull;
    __syncthreads();
    for (int i = tid; i < G; i += BS) {
        unsigned long long key = gtKey[c * G + i];
        if (key != 0ull) k[atomicAdd(&cnt, 1)] = key;
    }
    __syncthreads();
    const int T = cnt;
    if (tid == 0) sortT[c] = T;
    for (int t = tid; t < T; t += BS) {
        unsigned long long key = k[t];
        int pos = 0;
        for (int u = 0; u < T; ++u) pos += (k[u] > key) ? 1 : 0;   // keys unique
        sk[pos] = key;
    }
    __syncthreads();
    for (int j = tid; j < 1024; j += BS) sortedKeys[c * 1024 + j] = sk[j];
}

// ---------------- hist: pos(q) for every pred via binary search ----------
// Scores read straight from pred (identical bits to r[2]; pred is L3-hot) —
// the scoreC staging buffer is gone.
__global__ __launch_bounds__(BS) void hist_kernel(
        const float* __restrict__ pred,
        const unsigned long long* __restrict__ sortedKeys,
        int* __restrict__ gHist) {
    __shared__ unsigned long long sK[1024];
    __shared__ int h[1024];
    const int c = blockIdx.y, tid = threadIdx.x;
    for (int j = tid; j < 1024; j += BS) { sK[j] = sortedKeys[c * 1024 + j]; h[j] = 0; }
    __syncthreads();
    const int start = blockIdx.x * CHSZ;
    const int end   = min(start + CHSZ, P);
    const float* pr = pred + (size_t)c * P * 7;
    for (int i = start + tid; i < end; i += BS) {
        unsigned long long kq =
            ((unsigned long long)__float_as_uint(pr[(size_t)i * 7 + 2]) << 32)
            | (unsigned)(P - 1 - i);
        int lo = 0;   // count of sorted-desc keys > kq (pads are 0, never > kq)
        #pragma unroll
        for (int step = 512; step > 0; step >>= 1)
            if (sK[lo + step - 1] > kq) lo += step;
        atomicAdd(&h[lo], 1);
    }
    __syncthreads();
    for (int j = tid; j < 1024; j += BS)
        if (h[j]) atomicAdd(&gHist[c * 1024 + j], h[j]);   // no-return
}

// ---------------- ap + mean: prefix over hist + closed-form + last-block ----
// The mean fold uses the standard threadfence+ticket pattern: the last block
// to finish sums ap[0..79] sequentially (same order as the old mean_kernel ->
// bit-identical output). doneCnt zeroed in gt_bin.
__global__ __launch_bounds__(BS) void ap2m_kernel(
        const int* __restrict__ sortT, const int* __restrict__ gHist,
        float* __restrict__ ap, unsigned int* __restrict__ doneCnt,
        float* __restrict__ out) {
    __shared__ int ha[1024];
    __shared__ int hb[1024];
    __shared__ float red[BS];
    const int c = blockIdx.x, tid = threadIdx.x;
    const int T = sortT[c];
    for (int j = tid; j < 1024; j += BS) ha[j] = gHist[c * 1024 + j];
    __syncthreads();
    int* src = ha; int* dst = hb;
    for (int o = 1; o < 1024; o <<= 1) {
        for (int j = tid; j < 1024; j += BS)
            dst[j] = src[j] + ((j >= o) ? src[j - o] : 0);
        __syncthreads();
        int* tmp = src; src = dst; dst = tmp;
    }
    float sum = 0.0f;
    for (int s = tid; s < T; s += BS) {
        int r = src[s] - 1;          // inclusive prefix minus self
        if (r >= 1) {
            float kf  = (float)(s + 1);
            float km  = (float)s;
            float ri  = __fdiv_rn(kf, 800.0f);
            float rim = __fdiv_rn(km, 800.0f);
            float pi  = __fdiv_rn(kf, (float)(r + 1));
            float pim = __fdiv_rn(km, (float)r);
            sum = __fadd_rn(sum,
                  __fmul_rn(__fmul_rn(__fsub_rn(ri, rim), __fadd_rn(pi, pim)), 0.5f));
        }
    }
    red[tid] = sum;
    __syncthreads();
    for (int s2 = BS / 2; s2 > 0; s2 >>= 1) {
        if (tid < s2) red[tid] = __fadd_rn(red[tid], red[tid + s2]);
        __syncthreads();
    }
    if (tid == 0) {
        ap[c] = red[0];
        __threadfence();                         // publish ap[c] device-wide
        unsigned int t = atomicAdd(doneCnt, 1u); // ticket
        if (t == C - 1) {                        // last block finishes the mean
            __threadfence();                     // acquire all ap[] writes
            float s = 0.0f;
            for (int c2 = 0; c2 < C; ++c2) s = __fadd_rn(s, ap[c2]);
            out[0] = __fdiv_rn(s, 80.0f);
        }
    }
}

extern "C" void kernel_launch(void* const* d_in, const int* in_sizes, int n_in,
                              void* d_out, int out_size, void* d_ws, size_t ws_size,
                              hipStream_t stream) {
    const float* pred = (const float*)d_in[0];   // [C, P, 7] f32
    const float* gt   = (const float*)d_in[1];   // [C, G, 7] f32
    float* out = (float*)d_out;

    // Workspace layout — 2,985,984 B total (scoreC and all pred-side scatter
    // plumbing eliminated). Re-poisoned 0xAA each call — gt_bin (incl. folded
    // inits: gtKey, gHist, doneCnt) / sortc / ap2m rewrite everything
    // read-before-write.
    char* ws = (char*)d_ws;
    int*                sortT      = (int*)               (ws + 0);         //     320 B
    float*              ap         = (float*)             (ws + 512);       //     320 B
    unsigned int*       doneCnt    = (unsigned int*)      (ws + 896);       //       4 B
    unsigned short*     gtCnt      = (unsigned short*)    (ws + 1024);      //  40960 B
    unsigned short*     gtOff      = (unsigned short*)    (ws + 41984);     //  40960 B
    unsigned short*     gtIdx      = (unsigned short*)    (ws + 82944);     // 128000 B
    float*              gtAbe      = (float*)             (ws + 210944);    // 256000 B
    float4*             gtBox      = (float4*)            (ws + 466944);    // 1.024 MB (16-aligned)
    unsigned long long* gtKey      = (unsigned long long*)(ws + 1490944);   // 512000 B
    unsigned long long* sortedKeys = (unsigned long long*)(ws + 2002944);   // 655360 B
    int*                gHist      = (int*)               (ws + 2658304);   // 327680 B
    // end: 2985984 B

    const int M_BLK = (P + TPB - 1) / TPB;   // 15

    gt_bin_kernel<<<C, BS, 0, stream>>>(gt, gtCnt, gtOff, gtBox, gtAbe, gtIdx,
                                        gtKey, gHist, doneCnt);
    match6_kernel<<<dim3(M_BLK, C), BS, 0, stream>>>(pred, gtOff, gtCnt, gtBox,
                                                     gtAbe, gtIdx, gtKey);
    sortc_kernel<<<C, BS, 0, stream>>>(gtKey, sortedKeys, sortT);
    hist_kernel<<<dim3(HCH, C), BS, 0, stream>>>(pred, sortedKeys, gHist);
    ap2m_kernel<<<C, BS, 0, stream>>>(sortT, gHist, ap, doneCnt, out);
}